// Round 6
// baseline (499.197 us; speedup 1.0000x reference)
//
#include <hip/hip_runtime.h>

#define N_NODES 100000
#define N_EDGES 3200000
#define NFEAT 512
#define NHID 256
#define NCLASS 64
#define FCAT 128   // 2*NCLASS

#define RPB 64                         // rows per bucket
#define NB 1563                        // ceil(N_NODES / RPB)
#define CHUNK 8192                     // edges per partition block
#define NCH 391                        // ceil(N_EDGES / CHUNK)

typedef __attribute__((ext_vector_type(8))) short short8;
typedef __attribute__((ext_vector_type(4))) float f32x4;

static __device__ __forceinline__ unsigned short f2bf(float f) {
    unsigned u = __float_as_uint(f);
    unsigned r = (u + 0x7FFF + ((u >> 16) & 1)) >> 16;  // RNE
    return (unsigned short)r;
}
static __device__ __forceinline__ float bf2f(unsigned s) {
    return __uint_as_float(s << 16);
}
static __device__ __forceinline__ short8 cvt8(float4 x, float4 y) {
    short8 r;
    r[0] = (short)f2bf(x.x); r[1] = (short)f2bf(x.y);
    r[2] = (short)f2bf(x.z); r[3] = (short)f2bf(x.w);
    r[4] = (short)f2bf(y.x); r[5] = (short)f2bf(y.y);
    r[6] = (short)f2bf(y.z); r[7] = (short)f2bf(y.w);
    return r;
}

// ---------------------------------------------------------------------------
// Weight prep
// ---------------------------------------------------------------------------
__global__ void k_prep_wcat(const float* __restrict__ W1, const float* __restrict__ W2,
                            const float* __restrict__ Wres, unsigned short* __restrict__ WT) {
    int k = blockIdx.x;        // 0..511
    int j = threadIdx.x;       // 0..127
    const float* wb = (j < NCLASS) ? W2 : Wres;
    int jj = j & (NCLASS - 1);
    const float* w1row = W1 + (size_t)k * NHID;
    float acc = 0.f;
    for (int m = 0; m < NHID; ++m)
        acc += w1row[m] * wb[(size_t)m * NCLASS + jj];
    WT[(size_t)j * NFEAT + k] = f2bf(acc);
}

__global__ void k_prep_c(const float* __restrict__ b1, const float* __restrict__ W2,
                         const float* __restrict__ Wres, const float* __restrict__ bres,
                         float* __restrict__ c2, float* __restrict__ cr) {
    int j = threadIdx.x;  // 0..127
    const float* wb = (j < NCLASS) ? W2 : Wres;
    int jj = j & (NCLASS - 1);
    float acc = 0.f;
    for (int m = 0; m < NHID; ++m)
        acc += b1[m] * wb[(size_t)m * NCLASS + jj];
    if (j < NCLASS) c2[jj] = acc;
    else            cr[jj] = acc + bres[jj];
}

// ---------------------------------------------------------------------------
// MFMA GEMM, barrier-free: A_bf16[N,128] = bf16(X[N,512] @ Wcat[512,128])
// One wave per 16 rows (grid 6250 = exact). A-frags direct from global f32
// (per row, 4 lane-groups read 128 contiguous B = 2 full lines); B-frags
// direct from L2-resident WT bf16. 2-deep ping-pong pipeline, fully unrolled.
// ---------------------------------------------------------------------------
#define LOADF(A0, A1, B, k0)                                                   \
    A0 = *(const float4*)(pA + (k0));                                          \
    A1 = *(const float4*)(pA + (k0) + 4);                                      \
    _Pragma("unroll")                                                          \
    for (int nf = 0; nf < 8; ++nf)                                             \
        B[nf] = *(const uint4*)(pB + (size_t)nf * 16 * NFEAT + (k0));

#define COMPF(A0, A1, B)                                                       \
    {                                                                          \
        short8 af = cvt8(A0, A1);                                              \
        _Pragma("unroll")                                                      \
        for (int nf = 0; nf < 8; ++nf)                                         \
            acc[nf] = __builtin_amdgcn_mfma_f32_16x16x32_bf16(                 \
                af, *(const short8*)&B[nf], acc[nf], 0, 0, 0);                 \
    }

__global__ __launch_bounds__(64) void k_gemm_a(const float* __restrict__ X,
                                               const unsigned short* __restrict__ WT,
                                               unsigned short* __restrict__ A) {
    int lane = threadIdx.x;            // 0..63
    int lr = lane & 15, ls = lane >> 4;
    int row = blockIdx.x * 16 + lr;    // grid covers exactly N_NODES
    const float* pA = X + (size_t)row * NFEAT + ls * 8;
    const unsigned short* pB = WT + (size_t)lr * NFEAT + ls * 8;

    f32x4 acc[8] = {};

    float4 p0a0, p0a1; uint4 p0b[8];
    float4 p1a0, p1a1; uint4 p1b[8];

    LOADF(p0a0, p0a1, p0b, 0);
#pragma unroll
    for (int t = 0; t < 8; ++t) {
        const int k1 = t * 64 + 32, k2 = t * 64 + 64;
        LOADF(p1a0, p1a1, p1b, k1);
        COMPF(p0a0, p0a1, p0b);
        if (k2 < NFEAT) { LOADF(p0a0, p0a1, p0b, k2); }
        COMPF(p1a0, p1a1, p1b);
    }

    // C/D layout: col = lane&15, row = (lane>>4)*4 + j
#pragma unroll
    for (int nf = 0; nf < 8; ++nf) {
#pragma unroll
        for (int j = 0; j < 4; ++j) {
            int gr = blockIdx.x * 16 + ls * 4 + j;
            A[(size_t)gr * FCAT + nf * 16 + lr] = f2bf(acc[nf][j]);
        }
    }
}

// ---------------------------------------------------------------------------
// CSR build — atomic-free radix partition
// ---------------------------------------------------------------------------
__global__ __launch_bounds__(256) void k_hist_bkt(const int* __restrict__ rows,
                                                  int* __restrict__ HT) {
    __shared__ int h[NB];
    int c = blockIdx.x;
    for (int i = threadIdx.x; i < NB; i += 256) h[i] = 0;
    __syncthreads();
    int e0 = c * CHUNK;
    int eend = e0 + CHUNK; if (eend > N_EDGES) eend = N_EDGES;
    for (int e = e0 + threadIdx.x; e < eend; e += 256)
        atomicAdd(&h[rows[e] >> 6], 1);
    __syncthreads();
    for (int i = threadIdx.x; i < NB; i += 256)
        HT[(size_t)i * NCH + c] = h[i];
}

__global__ void k_scan_chunks(const int* __restrict__ HT, int* __restrict__ OFS,
                              int* __restrict__ T) {
    int b = blockIdx.x;
    int lane = threadIdx.x;  // 64
    const int* hb = HT + (size_t)b * NCH;
    int run = 0;
    for (int c0 = 0; c0 < NCH; c0 += 64) {
        int idx = c0 + lane;
        int v = (idx < NCH) ? hb[idx] : 0;
        int inc = v;
#pragma unroll
        for (int d = 1; d < 64; d <<= 1) {
            int t = __shfl_up(inc, d);
            if (lane >= d) inc += t;
        }
        if (idx < NCH) OFS[(size_t)idx * NB + b] = run + inc - v;
        run += __shfl(inc, 63);
    }
    if (lane == 0) T[b] = run;
}

__global__ void k_scan_base(const int* __restrict__ T, int* __restrict__ base,
                            int* __restrict__ row_ofs) {
    int lane = threadIdx.x;  // 64
    int run = 0;
    for (int c0 = 0; c0 < NB; c0 += 64) {
        int idx = c0 + lane;
        int v = (idx < NB) ? T[idx] : 0;
        int inc = v;
#pragma unroll
        for (int d = 1; d < 64; d <<= 1) {
            int t = __shfl_up(inc, d);
            if (lane >= d) inc += t;
        }
        if (idx < NB) base[idx] = run + inc - v;
        run += __shfl(inc, 63);
    }
    if (lane == 0) { base[NB] = run; row_ofs[N_NODES] = run; }
}

__global__ __launch_bounds__(256) void k_partition(const int* __restrict__ rows,
                                                   const int* __restrict__ cols,
                                                   const float* __restrict__ vals,
                                                   const int* __restrict__ OFS,
                                                   const int* __restrict__ base,
                                                   int2* __restrict__ stage) {
    __shared__ int cur[NB];
    int c = blockIdx.x;
    for (int i = threadIdx.x; i < NB; i += 256)
        cur[i] = base[i] + OFS[(size_t)c * NB + i];
    __syncthreads();
    int e0 = c * CHUNK;
    int eend = e0 + CHUNK; if (eend > N_EDGES) eend = N_EDGES;
    for (int e = e0 + threadIdx.x; e < eend; e += 256) {
        int r = rows[e];
        int p = atomicAdd(&cur[r >> 6], 1);
        stage[p] = make_int2(((r & 63) << 17) | cols[e], __float_as_int(vals[e]));
    }
}

__global__ __launch_bounds__(256) void k_csr(const int2* __restrict__ stage,
                                             const int* __restrict__ base,
                                             int* __restrict__ row_ofs,
                                             int2* __restrict__ csr) {
    __shared__ int cnt[RPB];
    __shared__ int cur[RPB];
    int b = blockIdx.x, t = threadIdx.x;
    int s = base[b], e = base[b + 1];
    if (t < RPB) cnt[t] = 0;
    __syncthreads();
    for (int i = s + t; i < e; i += 256)
        atomicAdd(&cnt[((unsigned)stage[i].x) >> 17], 1);
    __syncthreads();
    if (t < 64) {
        int v = cnt[t];
        int inc = v;
#pragma unroll
        for (int d = 1; d < 64; d <<= 1) {
            int u = __shfl_up(inc, d);
            if (t >= d) inc += u;
        }
        int ex = s + inc - v;
        int n = b * RPB + t;
        if (n < N_NODES) row_ofs[n] = ex;
        cur[t] = ex;
    }
    __syncthreads();
    for (int i = s + t; i < e; i += 256) {
        int2 ev = stage[i];
        int rl = ((unsigned)ev.x) >> 17;
        int p = atomicAdd(&cur[rl], 1);
        csr[p] = make_int2(ev.x & 0x1FFFF, ev.y);
    }
}

// ---------------------------------------------------------------------------
// SpMM 1: 8-deep pipelined gather of bf16 A rows (256 B/edge).
// ---------------------------------------------------------------------------
__global__ __launch_bounds__(256) void k_spmm1(const unsigned* __restrict__ A32,
                                               const int* __restrict__ row_ofs,
                                               const int2* __restrict__ csr,
                                               unsigned* __restrict__ S1a,
                                               float2* __restrict__ S1r) {
    int wv = threadIdx.x >> 6, lane = threadIdx.x & 63;
    int node = blockIdx.x * 4 + wv;
    if (node >= N_NODES) return;
    int s = row_ofs[node], e = row_ofs[node + 1];
    float a0 = 0.f, a1 = 0.f;
    int t = s;
    for (; t + 8 <= e; t += 8) {
        int2 cv[8];
#pragma unroll
        for (int u = 0; u < 8; ++u) cv[u] = csr[t + u];
        unsigned p[8];
#pragma unroll
        for (int u = 0; u < 8; ++u) p[u] = A32[cv[u].x * 64 + lane];
#pragma unroll
        for (int u = 0; u < 8; ++u) {
            float v = __int_as_float(cv[u].y);
            a0 += v * bf2f(p[u] & 0xffffu);
            a1 += v * bf2f(p[u] >> 16);
        }
    }
    for (; t < e; ++t) {
        int2 cv = csr[t];
        unsigned p = A32[cv.x * 64 + lane];
        float v = __int_as_float(cv.y);
        a0 += v * bf2f(p & 0xffffu);
        a1 += v * bf2f(p >> 16);
    }
    if (lane < 32)
        S1a[node * 32 + lane] = (unsigned)f2bf(a0) | ((unsigned)f2bf(a1) << 16);
    else
        S1r[node * 32 + (lane - 32)] = make_float2(a0, a1);
}

// ---------------------------------------------------------------------------
// SpMM 2 + fused epilogue: 8-deep pipelined gather of bf16 S1a rows (128 B/edge)
// ---------------------------------------------------------------------------
__global__ __launch_bounds__(256) void k_spmm2_out(const unsigned short* __restrict__ S1a16,
                                                   const float* __restrict__ S1r,
                                                   const int* __restrict__ row_ofs,
                                                   const int2* __restrict__ csr,
                                                   const float* __restrict__ c2,
                                                   const float* __restrict__ cr,
                                                   const float* __restrict__ b2,
                                                   float* __restrict__ out) {
    int wv = threadIdx.x >> 6, lane = threadIdx.x & 63;
    int node = blockIdx.x * 4 + wv;
    if (node >= N_NODES) return;
    int s = row_ofs[node], e = row_ofs[node + 1];
    float acc = 0.f, rsum = 0.f;
    int t = s;
    for (; t + 8 <= e; t += 8) {
        int2 cv[8];
#pragma unroll
        for (int u = 0; u < 8; ++u) cv[u] = csr[t + u];
        unsigned short p[8];
#pragma unroll
        for (int u = 0; u < 8; ++u) p[u] = S1a16[cv[u].x * 64 + lane];
#pragma unroll
        for (int u = 0; u < 8; ++u) {
            float v = __int_as_float(cv[u].y);
            rsum += v;
            acc += v * bf2f((unsigned)p[u]);
        }
    }
    for (; t < e; ++t) {
        int2 cv = csr[t];
        float v = __int_as_float(cv.y);
        rsum += v;
        acc += v * bf2f((unsigned)S1a16[cv.x * 64 + lane]);
    }
    float o = acc + rsum * c2[lane] + b2[lane];
    float res = S1r[node * 64 + lane] + cr[lane];
    out[node * 64 + lane] = fmaxf(o, 0.f) + res;
}

// ---------------------------------------------------------------------------
extern "C" void kernel_launch(void* const* d_in, const int* in_sizes, int n_in,
                              void* d_out, int out_size, void* d_ws, size_t ws_size,
                              hipStream_t stream) {
    const float* x        = (const float*)d_in[0];
    const int*   adj_rows = (const int*)d_in[1];
    const int*   adj_cols = (const int*)d_in[2];
    const float* adj_vals = (const float*)d_in[3];
    const float* W1       = (const float*)d_in[4];
    const float* b1       = (const float*)d_in[5];
    const float* W2       = (const float*)d_in[6];
    const float* b2       = (const float*)d_in[7];
    const float* Wres     = (const float*)d_in[8];
    const float* bres     = (const float*)d_in[9];
    float* out = (float*)d_out;

    char* ws = (char*)d_ws;
    size_t off = 0;
    auto alloc = [&](size_t bytes) {
        size_t o = off;
        off += (bytes + 511) & ~511ULL;
        return o;
    };

    unsigned short* WT  = (unsigned short*)(ws + alloc((size_t)NFEAT * FCAT * 2));
    float* c2           = (float*)(ws + alloc(NCLASS * 4));
    float* cr           = (float*)(ws + alloc(NCLASS * 4));
    // stage (CSR build) and A (GEMM/spmm1) time-share one 25.6 MB buffer
    char* unionbuf      = ws + alloc((size_t)N_EDGES * 8);
    int2* stage         = (int2*)unionbuf;
    unsigned short* A   = (unsigned short*)unionbuf;
    unsigned* S1a       = (unsigned*)(ws + alloc((size_t)N_NODES * 32 * 4));
    // S1r region time-shares with HT/OFS (dead after k_partition)
    char* s1r_region    = ws + alloc((size_t)N_NODES * 64 * 4);
    float* S1r          = (float*)s1r_region;
    int*   HT           = (int*)s1r_region;
    int*   OFS          = (int*)(s1r_region + ((size_t)NB * NCH * 4 + 511 & ~511ULL));
    int*   T            = (int*)(ws + alloc((size_t)NB * 4));
    int*   base         = (int*)(ws + alloc((size_t)(NB + 1) * 4));
    int*   row_ofs      = (int*)(ws + alloc((size_t)(N_NODES + 1) * 4));
    int2*  csr          = (int2*)(ws + alloc((size_t)N_EDGES * 8));
    (void)ws_size; (void)in_sizes; (void)n_in; (void)out_size;

    // weight prep (tiny)
    k_prep_wcat<<<NFEAT, FCAT, 0, stream>>>(W1, W2, Wres, WT);
    k_prep_c<<<1, FCAT, 0, stream>>>(b1, W2, Wres, bres, c2, cr);

    // CSR build: atomic-free partition + within-bucket sort
    k_hist_bkt<<<NCH, 256, 0, stream>>>(adj_rows, HT);
    k_scan_chunks<<<NB, 64, 0, stream>>>(HT, OFS, T);
    k_scan_base<<<1, 64, 0, stream>>>(T, base, row_ofs);
    k_partition<<<NCH, 256, 0, stream>>>(adj_rows, adj_cols, adj_vals, OFS, base, stage);
    k_csr<<<NB, 256, 0, stream>>>(stage, base, row_ofs, csr);

    // dense MFMA GEMM: A = bf16(x @ Wcat)   (overwrites stage)
    k_gemm_a<<<N_NODES / 16, 64, 0, stream>>>(x, WT, A);

    // spmm 1: S1 = spmm(A)  (bf16 gather; overwrites HT/OFS region with S1r)
    k_spmm1<<<(N_NODES + 3) / 4, 256, 0, stream>>>((const unsigned*)A, row_ofs, csr,
                                                   S1a, (float2*)S1r);

    // spmm 2 + epilogue
    k_spmm2_out<<<(N_NODES + 3) / 4, 256, 0, stream>>>((const unsigned short*)S1a, S1r,
                                                       row_ofs, csr, c2, cr, b2, out);
}

// Round 7
// 427.339 us; speedup vs baseline: 1.1682x; 1.1682x over previous
//
#include <hip/hip_runtime.h>

#define N_NODES 100000
#define N_EDGES 3200000
#define NFEAT 512
#define NHID 256
#define NCLASS 64
#define FCAT 128   // 2*NCLASS

#define RPB 64                         // rows per bucket
#define NB 1563                        // ceil(N_NODES / RPB)
#define CHUNK 8192                     // edges per partition block
#define NCH 391                        // ceil(N_EDGES / CHUNK)

typedef __attribute__((ext_vector_type(8))) short short8;
typedef __attribute__((ext_vector_type(4))) float f32x4;

static __device__ __forceinline__ unsigned short f2bf(float f) {
    unsigned u = __float_as_uint(f);
    unsigned r = (u + 0x7FFF + ((u >> 16) & 1)) >> 16;  // RNE
    return (unsigned short)r;
}
static __device__ __forceinline__ float bf2f(unsigned s) {
    return __uint_as_float(s << 16);
}
static __device__ __forceinline__ short8 cvt8(float4 x, float4 y) {
    short8 r;
    r[0] = (short)f2bf(x.x); r[1] = (short)f2bf(x.y);
    r[2] = (short)f2bf(x.z); r[3] = (short)f2bf(x.w);
    r[4] = (short)f2bf(y.x); r[5] = (short)f2bf(y.y);
    r[6] = (short)f2bf(y.z); r[7] = (short)f2bf(y.w);
    return r;
}
__device__ __forceinline__ void gload_lds16(const unsigned short* g, unsigned short* l) {
    __builtin_amdgcn_global_load_lds(
        (const __attribute__((address_space(1))) unsigned int*)g,
        (__attribute__((address_space(3))) unsigned int*)l, 16, 0, 0);
}

// ---------------------------------------------------------------------------
// Weight prep
// ---------------------------------------------------------------------------
__global__ void k_prep_wcat(const float* __restrict__ W1, const float* __restrict__ W2,
                            const float* __restrict__ Wres, unsigned short* __restrict__ WT) {
    int k = blockIdx.x;        // 0..511
    int j = threadIdx.x;       // 0..127
    const float* wb = (j < NCLASS) ? W2 : Wres;
    int jj = j & (NCLASS - 1);
    const float* w1row = W1 + (size_t)k * NHID;
    float acc = 0.f;
    for (int m = 0; m < NHID; ++m)
        acc += w1row[m] * wb[(size_t)m * NCLASS + jj];
    WT[(size_t)j * NFEAT + k] = f2bf(acc);
}

__global__ void k_prep_c(const float* __restrict__ b1, const float* __restrict__ W2,
                         const float* __restrict__ Wres, const float* __restrict__ bres,
                         float* __restrict__ c2, float* __restrict__ cr) {
    int j = threadIdx.x;  // 0..127
    const float* wb = (j < NCLASS) ? W2 : Wres;
    int jj = j & (NCLASS - 1);
    float acc = 0.f;
    for (int m = 0; m < NHID; ++m)
        acc += b1[m] * wb[(size_t)m * NCLASS + jj];
    if (j < NCLASS) c2[jj] = acc;
    else            cr[jj] = acc + bres[jj];
}

// ---------------------------------------------------------------------------
// MFMA GEMM: A_bf16[N,128] = bf16(X[N,512] @ Wcat[512,128])
// 4 waves/block, 16 rows/wave (BM=64, grid 1563). A-frags direct from global
// f32 (coalesced stream). B double-buffered in LDS via global_load_lds with
// XOR-swizzle (pre-swizzled global source, swizzled ds_read). 1 barrier/step.
// ---------------------------------------------------------------------------
#define GBK 64
__global__ __launch_bounds__(256) void k_gemm_a(const float* __restrict__ X,
                                                const unsigned short* __restrict__ WT,
                                                unsigned short* __restrict__ A) {
    __shared__ __align__(16) unsigned short Bs[2][FCAT * GBK];  // 2 x 16 KB
    int tid = threadIdx.x;
    int lane = tid & 63, w = tid >> 6;
    int lr = lane & 15, ls = lane >> 4;
    int row = blockIdx.x * 64 + w * 16 + lr;
    if (row >= N_NODES) row = N_NODES - 1;  // tail clamp (loads only)
    const float* pA = X + (size_t)row * NFEAT;

// stage one 128x64 B-tile (16 KB): 4 x 256 lanes x 16B. LDS linear dest slot
// sidx = q*256+tid -> [n = sidx>>3][phys slot c8 = sidx&7]; content is
// pre-swizzled: WT[n][k0 + (c8 ^ (n&7))*8 ...+8]
#define STAGE(buf, k0)                                                         \
    {                                                                          \
        _Pragma("unroll")                                                      \
        for (int q = 0; q < 4; ++q) {                                          \
            int sidx = q * 256 + tid;                                          \
            int n = sidx >> 3, c8 = sidx & 7;                                  \
            const unsigned short* src =                                        \
                WT + (size_t)n * NFEAT + (k0) + ((c8 ^ (n & 7)) << 3);         \
            unsigned short* dst = &Bs[buf][(size_t)(q * 256 + w * 64) * 8];    \
            gload_lds16(src, dst);                                             \
        }                                                                      \
    }

    f32x4 acc[8] = {};
    STAGE(0, 0);
    __syncthreads();
    int cur = 0;

#pragma unroll
    for (int t = 0; t < 8; ++t) {
        const int k0 = t * GBK;
        // A fragments for this K-step (issued before STAGE so compiler can
        // wait vmcnt(4), leaving the prefetch in flight)
        float4 a00 = *(const float4*)(pA + k0 + ls * 8);
        float4 a01 = *(const float4*)(pA + k0 + ls * 8 + 4);
        float4 a10 = *(const float4*)(pA + k0 + 32 + ls * 8);
        float4 a11 = *(const float4*)(pA + k0 + 32 + ls * 8 + 4);
        if (t < 7) STAGE(cur ^ 1, k0 + GBK);

        short8 af0 = cvt8(a00, a01);
        short8 af1 = cvt8(a10, a11);
        const unsigned short* bb = &Bs[cur][0];
#pragma unroll
        for (int nf = 0; nf < 8; ++nf) {
            int n = nf * 16 + lr;
            int p0 = ls ^ (n & 7);          // kh=0: logical slot ls
            int p1 = (4 + ls) ^ (n & 7);    // kh=1: logical slot 4+ls
            short8 b0 = *(const short8*)(bb + (size_t)n * 64 + p0 * 8);
            short8 b1 = *(const short8*)(bb + (size_t)n * 64 + p1 * 8);
            acc[nf] = __builtin_amdgcn_mfma_f32_16x16x32_bf16(af0, b0, acc[nf], 0, 0, 0);
            acc[nf] = __builtin_amdgcn_mfma_f32_16x16x32_bf16(af1, b1, acc[nf], 0, 0, 0);
        }
        __syncthreads();
        cur ^= 1;
    }
#undef STAGE

    // C/D layout: col = lane&15, row = (lane>>4)*4 + j
#pragma unroll
    for (int j = 0; j < 4; ++j) {
        int gr = blockIdx.x * 64 + w * 16 + ls * 4 + j;
        if (gr < N_NODES) {
#pragma unroll
            for (int nf = 0; nf < 8; ++nf)
                A[(size_t)gr * FCAT + nf * 16 + lr] = f2bf(acc[nf][j]);
        }
    }
}

// ---------------------------------------------------------------------------
// CSR build — atomic-free radix partition
// ---------------------------------------------------------------------------
__global__ __launch_bounds__(256) void k_hist_bkt(const int* __restrict__ rows,
                                                  int* __restrict__ HT) {
    __shared__ int h[NB];
    int c = blockIdx.x;
    for (int i = threadIdx.x; i < NB; i += 256) h[i] = 0;
    __syncthreads();
    int e0 = c * CHUNK;
    int eend = e0 + CHUNK; if (eend > N_EDGES) eend = N_EDGES;
    for (int e = e0 + threadIdx.x; e < eend; e += 256)
        atomicAdd(&h[rows[e] >> 6], 1);
    __syncthreads();
    for (int i = threadIdx.x; i < NB; i += 256)
        HT[(size_t)i * NCH + c] = h[i];
}

__global__ void k_scan_chunks(const int* __restrict__ HT, int* __restrict__ OFS,
                              int* __restrict__ T) {
    int b = blockIdx.x;
    int lane = threadIdx.x;  // 64
    const int* hb = HT + (size_t)b * NCH;
    int run = 0;
    for (int c0 = 0; c0 < NCH; c0 += 64) {
        int idx = c0 + lane;
        int v = (idx < NCH) ? hb[idx] : 0;
        int inc = v;
#pragma unroll
        for (int d = 1; d < 64; d <<= 1) {
            int t = __shfl_up(inc, d);
            if (lane >= d) inc += t;
        }
        if (idx < NCH) OFS[(size_t)idx * NB + b] = run + inc - v;
        run += __shfl(inc, 63);
    }
    if (lane == 0) T[b] = run;
}

__global__ void k_scan_base(const int* __restrict__ T, int* __restrict__ base,
                            int* __restrict__ row_ofs) {
    int lane = threadIdx.x;  // 64
    int run = 0;
    for (int c0 = 0; c0 < NB; c0 += 64) {
        int idx = c0 + lane;
        int v = (idx < NB) ? T[idx] : 0;
        int inc = v;
#pragma unroll
        for (int d = 1; d < 64; d <<= 1) {
            int t = __shfl_up(inc, d);
            if (lane >= d) inc += t;
        }
        if (idx < NB) base[idx] = run + inc - v;
        run += __shfl(inc, 63);
    }
    if (lane == 0) { base[NB] = run; row_ofs[N_NODES] = run; }
}

__global__ __launch_bounds__(256) void k_partition(const int* __restrict__ rows,
                                                   const int* __restrict__ cols,
                                                   const float* __restrict__ vals,
                                                   const int* __restrict__ OFS,
                                                   const int* __restrict__ base,
                                                   int2* __restrict__ stage) {
    __shared__ int cur[NB];
    int c = blockIdx.x;
    for (int i = threadIdx.x; i < NB; i += 256)
        cur[i] = base[i] + OFS[(size_t)c * NB + i];
    __syncthreads();
    int e0 = c * CHUNK;
    int eend = e0 + CHUNK; if (eend > N_EDGES) eend = N_EDGES;
    for (int e = e0 + threadIdx.x; e < eend; e += 256) {
        int r = rows[e];
        int p = atomicAdd(&cur[r >> 6], 1);
        stage[p] = make_int2(((r & 63) << 17) | cols[e], __float_as_int(vals[e]));
    }
}

__global__ __launch_bounds__(256) void k_csr(const int2* __restrict__ stage,
                                             const int* __restrict__ base,
                                             int* __restrict__ row_ofs,
                                             int2* __restrict__ csr) {
    __shared__ int cnt[RPB];
    __shared__ int cur[RPB];
    int b = blockIdx.x, t = threadIdx.x;
    int s = base[b], e = base[b + 1];
    if (t < RPB) cnt[t] = 0;
    __syncthreads();
    for (int i = s + t; i < e; i += 256)
        atomicAdd(&cnt[((unsigned)stage[i].x) >> 17], 1);
    __syncthreads();
    if (t < 64) {
        int v = cnt[t];
        int inc = v;
#pragma unroll
        for (int d = 1; d < 64; d <<= 1) {
            int u = __shfl_up(inc, d);
            if (t >= d) inc += u;
        }
        int ex = s + inc - v;
        int n = b * RPB + t;
        if (n < N_NODES) row_ofs[n] = ex;
        cur[t] = ex;
    }
    __syncthreads();
    for (int i = s + t; i < e; i += 256) {
        int2 ev = stage[i];
        int rl = ((unsigned)ev.x) >> 17;
        int p = atomicAdd(&cur[rl], 1);
        csr[p] = make_int2(ev.x & 0x1FFFF, ev.y);
    }
}

// ---------------------------------------------------------------------------
// SpMM 1: 8-deep pipelined gather of bf16 A rows (256 B/edge).
// ---------------------------------------------------------------------------
__global__ __launch_bounds__(256) void k_spmm1(const unsigned* __restrict__ A32,
                                               const int* __restrict__ row_ofs,
                                               const int2* __restrict__ csr,
                                               unsigned* __restrict__ S1a,
                                               float2* __restrict__ S1r) {
    int wv = threadIdx.x >> 6, lane = threadIdx.x & 63;
    int node = blockIdx.x * 4 + wv;
    if (node >= N_NODES) return;
    int s = row_ofs[node], e = row_ofs[node + 1];
    float a0 = 0.f, a1 = 0.f;
    int t = s;
    for (; t + 8 <= e; t += 8) {
        int2 cv[8];
#pragma unroll
        for (int u = 0; u < 8; ++u) cv[u] = csr[t + u];
        unsigned p[8];
#pragma unroll
        for (int u = 0; u < 8; ++u) p[u] = A32[cv[u].x * 64 + lane];
#pragma unroll
        for (int u = 0; u < 8; ++u) {
            float v = __int_as_float(cv[u].y);
            a0 += v * bf2f(p[u] & 0xffffu);
            a1 += v * bf2f(p[u] >> 16);
        }
    }
    for (; t < e; ++t) {
        int2 cv = csr[t];
        unsigned p = A32[cv.x * 64 + lane];
        float v = __int_as_float(cv.y);
        a0 += v * bf2f(p & 0xffffu);
        a1 += v * bf2f(p >> 16);
    }
    if (lane < 32)
        S1a[node * 32 + lane] = (unsigned)f2bf(a0) | ((unsigned)f2bf(a1) << 16);
    else
        S1r[node * 32 + (lane - 32)] = make_float2(a0, a1);
}

// ---------------------------------------------------------------------------
// SpMM 2 + fused epilogue: 8-deep pipelined gather of bf16 S1a rows (128 B/edge)
// ---------------------------------------------------------------------------
__global__ __launch_bounds__(256) void k_spmm2_out(const unsigned short* __restrict__ S1a16,
                                                   const float* __restrict__ S1r,
                                                   const int* __restrict__ row_ofs,
                                                   const int2* __restrict__ csr,
                                                   const float* __restrict__ c2,
                                                   const float* __restrict__ cr,
                                                   const float* __restrict__ b2,
                                                   float* __restrict__ out) {
    int wv = threadIdx.x >> 6, lane = threadIdx.x & 63;
    int node = blockIdx.x * 4 + wv;
    if (node >= N_NODES) return;
    int s = row_ofs[node], e = row_ofs[node + 1];
    float acc = 0.f, rsum = 0.f;
    int t = s;
    for (; t + 8 <= e; t += 8) {
        int2 cv[8];
#pragma unroll
        for (int u = 0; u < 8; ++u) cv[u] = csr[t + u];
        unsigned short p[8];
#pragma unroll
        for (int u = 0; u < 8; ++u) p[u] = S1a16[cv[u].x * 64 + lane];
#pragma unroll
        for (int u = 0; u < 8; ++u) {
            float v = __int_as_float(cv[u].y);
            rsum += v;
            acc += v * bf2f((unsigned)p[u]);
        }
    }
    for (; t < e; ++t) {
        int2 cv = csr[t];
        float v = __int_as_float(cv.y);
        rsum += v;
        acc += v * bf2f((unsigned)S1a16[cv.x * 64 + lane]);
    }
    float o = acc + rsum * c2[lane] + b2[lane];
    float res = S1r[node * 64 + lane] + cr[lane];
    out[node * 64 + lane] = fmaxf(o, 0.f) + res;
}

// ---------------------------------------------------------------------------
extern "C" void kernel_launch(void* const* d_in, const int* in_sizes, int n_in,
                              void* d_out, int out_size, void* d_ws, size_t ws_size,
                              hipStream_t stream) {
    const float* x        = (const float*)d_in[0];
    const int*   adj_rows = (const int*)d_in[1];
    const int*   adj_cols = (const int*)d_in[2];
    const float* adj_vals = (const float*)d_in[3];
    const float* W1       = (const float*)d_in[4];
    const float* b1       = (const float*)d_in[5];
    const float* W2       = (const float*)d_in[6];
    const float* b2       = (const float*)d_in[7];
    const float* Wres     = (const float*)d_in[8];
    const float* bres     = (const float*)d_in[9];
    float* out = (float*)d_out;

    char* ws = (char*)d_ws;
    size_t off = 0;
    auto alloc = [&](size_t bytes) {
        size_t o = off;
        off += (bytes + 511) & ~511ULL;
        return o;
    };

    unsigned short* WT  = (unsigned short*)(ws + alloc((size_t)NFEAT * FCAT * 2));
    float* c2           = (float*)(ws + alloc(NCLASS * 4));
    float* cr           = (float*)(ws + alloc(NCLASS * 4));
    // stage (CSR build) and A (GEMM/spmm1) time-share one 25.6 MB buffer
    char* unionbuf      = ws + alloc((size_t)N_EDGES * 8);
    int2* stage         = (int2*)unionbuf;
    unsigned short* A   = (unsigned short*)unionbuf;
    unsigned* S1a       = (unsigned*)(ws + alloc((size_t)N_NODES * 32 * 4));
    // S1r region time-shares with HT/OFS (dead after k_partition)
    char* s1r_region    = ws + alloc((size_t)N_NODES * 64 * 4);
    float* S1r          = (float*)s1r_region;
    int*   HT           = (int*)s1r_region;
    int*   OFS          = (int*)(s1r_region + ((size_t)NB * NCH * 4 + 511 & ~511ULL));
    int*   T            = (int*)(ws + alloc((size_t)NB * 4));
    int*   base         = (int*)(ws + alloc((size_t)(NB + 1) * 4));
    int*   row_ofs      = (int*)(ws + alloc((size_t)(N_NODES + 1) * 4));
    int2*  csr          = (int2*)(ws + alloc((size_t)N_EDGES * 8));
    (void)ws_size; (void)in_sizes; (void)n_in; (void)out_size;

    // weight prep (tiny)
    k_prep_wcat<<<NFEAT, FCAT, 0, stream>>>(W1, W2, Wres, WT);
    k_prep_c<<<1, FCAT, 0, stream>>>(b1, W2, Wres, bres, c2, cr);

    // CSR build: atomic-free partition + within-bucket sort
    k_hist_bkt<<<NCH, 256, 0, stream>>>(adj_rows, HT);
    k_scan_chunks<<<NB, 64, 0, stream>>>(HT, OFS, T);
    k_scan_base<<<1, 64, 0, stream>>>(T, base, row_ofs);
    k_partition<<<NCH, 256, 0, stream>>>(adj_rows, adj_cols, adj_vals, OFS, base, stage);
    k_csr<<<NB, 256, 0, stream>>>(stage, base, row_ofs, csr);

    // dense MFMA GEMM: A = bf16(x @ Wcat)   (overwrites stage)
    k_gemm_a<<<(N_NODES + 63) / 64, 256, 0, stream>>>(x, WT, A);

    // spmm 1: S1 = spmm(A)  (bf16 gather; overwrites HT/OFS region with S1r)
    k_spmm1<<<(N_NODES + 3) / 4, 256, 0, stream>>>((const unsigned*)A, row_ofs, csr,
                                                   S1a, (float2*)S1r);

    // spmm 2 + epilogue
    k_spmm2_out<<<(N_NODES + 3) / 4, 256, 0, stream>>>((const unsigned short*)S1a, S1r,
                                                       row_ofs, csr, c2, cr, b2, out);
}